// Round 5
// baseline (1645.310 us; speedup 1.0000x reference)
//
#include <hip/hip_runtime.h>

#define N_NODES 100000
#define N_EDGES 1600000
#define D_IN    256
#define D_OUT   128

#define BROWS    128                                   // rows per bucket
#define NBUCKETS ((N_NODES + BROWS - 1) / BROWS)       // 782
#define EPB      4096                                  // edges per partition block
#define NPART    ((N_EDGES + EPB - 1) / EPB)           // 391

typedef __attribute__((ext_vector_type(8))) short short8;   // 8 bf16 (4 VGPRs)
typedef __attribute__((ext_vector_type(4))) float floatx4;  // MFMA C/D frag

static __device__ __forceinline__ ushort f2bf(float f) {
    union { float f; unsigned u; } v; v.f = f;
    unsigned r = v.u + 0x7fffu + ((v.u >> 16) & 1u);   // RNE truncate to bf16
    return (ushort)(r >> 16);
}

// ---------------------------------------------------------------------------
// GEMM: support(bf16) = X @ W via mfma_f32_16x16x32_bf16.  (unchanged from R4)
// ---------------------------------------------------------------------------
__global__ __launch_bounds__(256) void gcn_gemm_mfma(
    const float* __restrict__ X,
    const float* __restrict__ W,
    ushort* __restrict__ supp)
{
    __shared__ ushort wp[32 * 128 * 8];   // 64 KiB packed bf16 W

    const int tid  = threadIdx.x;
    const int lane = tid & 63;
    const int wid  = tid >> 6;            // wave 0..3
    const int node0 = blockIdx.x * 128;

#pragma unroll
    for (int i = 0; i < 16; ++i) {
        const int p   = i * 256 + tid;     // 4096 (kg,col) pairs
        const int kg  = p >> 7;
        const int col = p & 127;
        const float* wsrc = W + (size_t)(kg * 8) * D_OUT + col;
        short8 v;
#pragma unroll
        for (int ki = 0; ki < 8; ++ki)
            v[ki] = (short)f2bf(wsrc[(size_t)ki * D_OUT]);
        *(short8*)&wp[(size_t)p * 8] = v;
    }
    __syncthreads();

    const int r0    = node0 + wid * 32;
    const int g     = lane >> 4;
    const int arow0 = r0 + (lane & 15);
    const int arow1 = arow0 + 16;
    const int crow0 = arow0 < N_NODES - 1 ? arow0 : N_NODES - 1;
    const int crow1 = arow1 < N_NODES - 1 ? arow1 : N_NODES - 1;

    const float* xp0 = X + (size_t)crow0 * D_IN + g * 8;
    const float* xp1 = X + (size_t)crow1 * D_IN + g * 8;

    floatx4 acc[2][8];
#pragma unroll
    for (int t = 0; t < 2; ++t)
#pragma unroll
        for (int n = 0; n < 8; ++n)
            acc[t][n] = (floatx4){0.f, 0.f, 0.f, 0.f};

#pragma unroll
    for (int ks = 0; ks < 8; ++ks) {
        const float4 u0 = *(const float4*)(xp0 + ks * 32);
        const float4 u1 = *(const float4*)(xp0 + ks * 32 + 4);
        const float4 u2 = *(const float4*)(xp1 + ks * 32);
        const float4 u3 = *(const float4*)(xp1 + ks * 32 + 4);
        short8 a0, a1;
        a0[0] = (short)f2bf(u0.x); a0[1] = (short)f2bf(u0.y);
        a0[2] = (short)f2bf(u0.z); a0[3] = (short)f2bf(u0.w);
        a0[4] = (short)f2bf(u1.x); a0[5] = (short)f2bf(u1.y);
        a0[6] = (short)f2bf(u1.z); a0[7] = (short)f2bf(u1.w);
        a1[0] = (short)f2bf(u2.x); a1[1] = (short)f2bf(u2.y);
        a1[2] = (short)f2bf(u2.z); a1[3] = (short)f2bf(u2.w);
        a1[4] = (short)f2bf(u3.x); a1[5] = (short)f2bf(u3.y);
        a1[6] = (short)f2bf(u3.z); a1[7] = (short)f2bf(u3.w);

        const int kg = ks * 4 + g;
#pragma unroll
        for (int n = 0; n < 8; ++n) {
            const short8 b = *(const short8*)&wp[(size_t)((kg << 7) + n * 16 + (lane & 15)) * 8];
            acc[0][n] = __builtin_amdgcn_mfma_f32_16x16x32_bf16(a0, b, acc[0][n], 0, 0, 0);
            acc[1][n] = __builtin_amdgcn_mfma_f32_16x16x32_bf16(a1, b, acc[1][n], 0, 0, 0);
        }
    }

#pragma unroll
    for (int t = 0; t < 2; ++t) {
        const int rbase = r0 + t * 16 + (lane >> 4) * 4;
#pragma unroll
        for (int n = 0; n < 8; ++n) {
            const int col = n * 16 + (lane & 15);
#pragma unroll
            for (int i = 0; i < 4; ++i) {
                const int row = rbase + i;
                if (row < N_NODES)
                    supp[(size_t)row * D_OUT + col] = f2bf(acc[t][n][i]);
            }
        }
    }
}

// ---------------------------------------------------------------------------
// Bucket counts: per-block LDS histogram of (row >> 7), then bulk atomics.
// ---------------------------------------------------------------------------
__global__ __launch_bounds__(256) void gcn_bcount(
    const int* __restrict__ rows, int* __restrict__ bcount)
{
    __shared__ int h[NBUCKETS];
    const int tid = threadIdx.x;
    for (int i = tid; i < NBUCKETS; i += 256) h[i] = 0;
    __syncthreads();

    const int e0 = blockIdx.x * EPB;
#pragma unroll
    for (int i = 0; i < EPB / 256; ++i) {
        const int e = e0 + i * 256 + tid;
        if (e < N_EDGES) atomicAdd(&h[rows[e] >> 7], 1);
    }
    __syncthreads();

    for (int i = tid; i < NBUCKETS; i += 256) {
        const int c = h[i];
        if (c) atomicAdd(&bcount[i], c);
    }
}

// ---------------------------------------------------------------------------
// Exclusive scan of 782 bucket counts (single block); init global cursors.
// ---------------------------------------------------------------------------
__global__ __launch_bounds__(256) void gcn_bscan(
    const int* __restrict__ bcount, int* __restrict__ boff, int* __restrict__ gcursor)
{
    __shared__ int t[256];
    const int tid = threadIdx.x;
    const int i0 = tid * 4;

    int c0 = 0, c1 = 0, c2 = 0, c3 = 0;
    if (i0 + 0 < NBUCKETS) c0 = bcount[i0 + 0];
    if (i0 + 1 < NBUCKETS) c1 = bcount[i0 + 1];
    if (i0 + 2 < NBUCKETS) c2 = bcount[i0 + 2];
    if (i0 + 3 < NBUCKETS) c3 = bcount[i0 + 3];
    const int s = c0 + c1 + c2 + c3;
    t[tid] = s;
    __syncthreads();

    for (int d = 1; d < 256; d <<= 1) {
        int x = t[tid];
        int add = (tid >= d) ? t[tid - d] : 0;
        __syncthreads();
        t[tid] = x + add;
        __syncthreads();
    }
    const int excl = t[tid] - s;

    const int e0 = excl;
    const int e1 = e0 + c0;
    const int e2 = e1 + c1;
    const int e3 = e2 + c2;
    if (i0 + 0 < NBUCKETS) { boff[i0 + 0] = e0; gcursor[i0 + 0] = e0; }
    if (i0 + 1 < NBUCKETS) { boff[i0 + 1] = e1; gcursor[i0 + 1] = e1; }
    if (i0 + 2 < NBUCKETS) { boff[i0 + 2] = e2; gcursor[i0 + 2] = e2; }
    if (i0 + 3 < NBUCKETS) { boff[i0 + 3] = e3; gcursor[i0 + 3] = e3; }
}

// ---------------------------------------------------------------------------
// Bucket scatter: per-block LDS hist -> bulk reservation (1 atomic per
// nonempty bucket per block) -> per-edge LDS cursor -> direct global write.
// Payload: ((row & 127) << 17) | col  (24 bits), plus val bits.
// ---------------------------------------------------------------------------
__global__ __launch_bounds__(256) void gcn_bscatter(
    const int* __restrict__ rows, const int* __restrict__ cols,
    const float* __restrict__ vals, int* __restrict__ gcursor,
    int2* __restrict__ edges)
{
    __shared__ int h[NBUCKETS];   // hist, then global-base cursor
    const int tid = threadIdx.x;
    for (int i = tid; i < NBUCKETS; i += 256) h[i] = 0;
    __syncthreads();

    const int e0 = blockIdx.x * EPB;
    int bk[EPB / 256];
    int rl[EPB / 256];
#pragma unroll
    for (int i = 0; i < EPB / 256; ++i) {
        const int e = e0 + i * 256 + tid;
        bk[i] = -1;
        if (e < N_EDGES) {
            const int r = rows[e];
            bk[i] = r >> 7;
            rl[i] = r & 127;
            atomicAdd(&h[bk[i]], 1);
        }
    }
    __syncthreads();

    // reserve contiguous space per bucket; h[i] becomes the running cursor
    for (int i = tid; i < NBUCKETS; i += 256) {
        const int c = h[i];
        h[i] = c ? atomicAdd(&gcursor[i], c) : 0;
    }
    __syncthreads();

#pragma unroll
    for (int i = 0; i < EPB / 256; ++i) {
        if (bk[i] >= 0) {
            const int e = e0 + i * 256 + tid;
            const int pos = atomicAdd(&h[bk[i]], 1);
            edges[pos] = make_int2((rl[i] << 17) | cols[e], __float_as_int(vals[e]));
        }
    }
}

// ---------------------------------------------------------------------------
// Aggregate + ReLU, one block per 128-row bucket.
// 64 KB LDS accumulator in two planes (even/odd cols) so ds_add_f32 addresses
// are rl*64+lane -> 2 lanes/bank (free).  Edges streamed coalesced per wave,
// broadcast via __shfl; support gathers are 256 B contiguous, L3-resident.
// ---------------------------------------------------------------------------
__global__ __launch_bounds__(256) void gcn_baggregate(
    const int* __restrict__ boff, const int* __restrict__ bcount,
    const int2* __restrict__ edges, const unsigned* __restrict__ supp2,
    float* __restrict__ out)
{
    __shared__ float accL[BROWS * 64];   // cols 2c   (32 KB)
    __shared__ float accH[BROWS * 64];   // cols 2c+1 (32 KB)

    const int tid  = threadIdx.x;
    const int lane = tid & 63;
    const int wid  = tid >> 6;

    {
        float4 z = make_float4(0.f, 0.f, 0.f, 0.f);
        float4* aL = (float4*)accL;
        float4* aH = (float4*)accH;
#pragma unroll
        for (int i = 0; i < 8; ++i) { aL[i * 256 + tid] = z; aH[i * 256 + tid] = z; }
    }
    __syncthreads();

    const int bkt   = blockIdx.x;
    const int start = boff[bkt];
    const int end   = start + bcount[bkt];

    for (int base = start + wid * 64; base < end; base += 256) {
        int m = end - base;
        if (m > 64) m = 64;
        int2 e = edges[base + (lane < m ? lane : 0)];
#pragma unroll 4
        for (int j = 0; j < m; ++j) {
            const int   packed = __shfl(e.x, j);
            const float v      = __int_as_float(__shfl(e.y, j));
            const int   col    = packed & 0x1ffff;
            const int   rl     = packed >> 17;
            const unsigned s   = supp2[(size_t)col * 64 + lane];
            const float lo = __uint_as_float(s << 16);
            const float hi = __uint_as_float(s & 0xffff0000u);
            atomicAdd(&accL[rl * 64 + lane], v * lo);
            atomicAdd(&accH[rl * 64 + lane], v * hi);
        }
    }
    __syncthreads();

    // writeback with fused ReLU: out[node0+rl][2c]=accL[rl][c], [2c+1]=accH[rl][c]
    const int node0 = bkt * BROWS;
    float2* o2 = (float2*)out;
#pragma unroll
    for (int i = 0; i < 32; ++i) {
        const int f  = i * 256 + tid;     // float2 index within bucket
        const int rl = f >> 6;
        const int c  = f & 63;
        const int row = node0 + rl;
        if (row < N_NODES) {
            const float x = accL[rl * 64 + c];
            const float y = accH[rl * 64 + c];
            float2 w;
            w.x = x > 0.f ? x : 0.f;
            w.y = y > 0.f ? y : 0.f;
            o2[(size_t)row * 64 + c] = w;
        }
    }
}

extern "C" void kernel_launch(void* const* d_in, const int* in_sizes, int n_in,
                              void* d_out, int out_size, void* d_ws, size_t ws_size,
                              hipStream_t stream)
{
    const float* X    = (const float*)d_in[0];   // [N_NODES, D_IN]
    const float* W    = (const float*)d_in[1];   // [D_IN, D_OUT]
    const int*   rows = (const int*)  d_in[2];   // [N_EDGES]
    const int*   cols = (const int*)  d_in[3];   // [N_EDGES]
    const float* vals = (const float*)d_in[4];   // [N_EDGES]
    float* out = (float*)d_out;                  // [N_NODES, D_OUT]

    // ---- workspace layout (16B aligned) ----
    char* ws = (char*)d_ws;
    size_t p = 0;
    ushort* supp    = (ushort*)(ws + p); p += (size_t)N_NODES * D_OUT * 2;  // 25.6 MB
    int*    bcount  = (int*)   (ws + p); p += (size_t)NBUCKETS * 4;
    int*    boff    = (int*)   (ws + p); p += (size_t)NBUCKETS * 4;
    int*    gcursor = (int*)   (ws + p); p += (size_t)NBUCKETS * 4;
    p = (p + 15) & ~(size_t)15;
    int2*   edges   = (int2*)  (ws + p); p += (size_t)N_EDGES * 8;          // 12.8 MB
    (void)ws_size;

    // 1) support = bf16(X @ W)  (MFMA)
    gcn_gemm_mfma<<<(N_NODES + 127) / 128, 256, 0, stream>>>(X, W, supp);

    // 2) bucket partition (128-row buckets)
    (void)hipMemsetAsync(bcount, 0, (size_t)NBUCKETS * 4, stream);
    gcn_bcount<<<NPART, 256, 0, stream>>>(rows, bcount);
    gcn_bscan<<<1, 256, 0, stream>>>(bcount, boff, gcursor);
    gcn_bscatter<<<NPART, 256, 0, stream>>>(rows, cols, vals, gcursor, edges);

    // 3) out = ReLU(A @ support) — LDS-accumulator per bucket, no fp global atomics
    gcn_baggregate<<<NBUCKETS, 256, 0, stream>>>(
        boff, bcount, edges, (const unsigned*)supp, out);
}